// Round 1
// 84.377 us; speedup vs baseline: 1.0380x; 1.0380x over previous
//
#include <hip/hip_runtime.h>
#include <hip/hip_fp16.h>

#define Bb 64
#define Ll 32
#define Hh 128
#define Oo 16384
#define Cc 32
#define TOo 64
#define NT 1024

typedef _Float16 h2 __attribute__((ext_vector_type(2)));

// round-to-nearest pack of two f32 into a half2 bit pattern (setup paths only)
static __device__ __forceinline__ unsigned pk_rn(float x, float y) {
    unsigned short ux = __half_as_ushort(__float2half_rn(x));
    unsigned short uy = __half_as_ushort(__float2half_rn(y));
    return (unsigned)ux | ((unsigned)uy << 16);
}
static __device__ __forceinline__ h2 as_h2(unsigned u) {
    union { unsigned u; h2 h; } v; v.u = u; return v.h;
}
static __device__ __forceinline__ h2 habs2(h2 x) {   // v_and_b32 0x7FFF7FFF
    union { h2 h; unsigned u; } v; v.h = x; v.u &= 0x7FFF7FFFu; return v.h;
}

// ---------------------------------------------------------------------------
// prep: A[b,h] = relu(z@Wz+bz) @ W1[:H]  (f32), emitted packed as half2 pairs
//       SA2w[b] = sum_h 0.5*W2[h]*A[b,h]  (f32 — linear term stays exact)
// ---------------------------------------------------------------------------
__global__ __launch_bounds__(256) void prep_kernel(
    const float* __restrict__ z, const float* __restrict__ Wz,
    const float* __restrict__ bz, const float* __restrict__ W1,
    const float* __restrict__ W2,
    unsigned* __restrict__ A16, float* __restrict__ SA2w)
{
    __shared__ float pz[2][Hh];
    __shared__ float af[2][Hh];
    __shared__ float ps[2][Hh];
    const int t  = threadIdx.x;
    const int h  = t & (Hh - 1);
    const int bb = t >> 7;
    const int b  = blockIdx.x * 2 + bb;

    float v = bz[h];
#pragma unroll
    for (int c = 0; c < Ll; ++c)
        v = fmaf(z[b * Ll + c], Wz[c * Hh + h], v);
    pz[bb][h] = fmaxf(v, 0.f);
    __syncthreads();

    float a = 0.f;
#pragma unroll
    for (int k = 0; k < Hh; ++k)
        a = fmaf(pz[bb][k], W1[k * Hh + h], a);
    af[bb][h] = a;
    ps[bb][h] = 0.5f * W2[h] * a;
    __syncthreads();

    if (h < Hh / 2)
        A16[b * (Hh / 2) + h] = pk_rn(af[bb][2 * h], af[bb][2 * h + 1]);

    if (h == 0) {
        float s = 0.f;
        for (int k = 0; k < Hh; ++k) s += ps[bb][k];
        SA2w[b] = s;
    }
}

// ---------------------------------------------------------------------------
// main: out[b,o] = SA2w[b] + b2 + sum_h w2h[h]*g[o,h] + sum_h w2h[h]*|A+g|
//   w2h = 0.5*W2  (w*relu(x) = 0.5*w*x + 0.5*w*|x|, exact)
// |A+g| term in f16: v_pk_add_f16 + v_and (abs) + v_dot2_f32_f16 (f32 acc)
//   = 3 VALU per 2 h  (vs 4 in f32) -> main loop 1024 -> 768 wave-instrs.
// Linear terms (sg, SA2w) stay f32. G phase uses fdot2 too (17 vs 33 per g).
// ---------------------------------------------------------------------------
__global__ __launch_bounds__(NT) void main_kernel(
    const unsigned* __restrict__ A16, const float* __restrict__ SA2w,
    const float* __restrict__ fe, const float* __restrict__ fb,
    const float* __restrict__ W1, const float* __restrict__ b1,
    const float* __restrict__ W2, const float* __restrict__ b2,
    float* __restrict__ out)
{
    __shared__ unsigned fe_h[TOo][Cc / 2];   // 4 KB  (half2 pairs along c)
    __shared__ float    gT[Hh][TOo + 1];     // 33.3 KB, stride 65: rotated banks
    __shared__ unsigned A_h[Bb][Hh / 2];     // 16 KB (half2 pairs along h)
    __shared__ float    part[4][Bb][TOo];    // 64 KB
    __shared__ float    w2_s[Hh];
    __shared__ float    fb_s[TOo];

    const int t  = threadIdx.x;
    const int o0 = blockIdx.x * TOo;

    // --- stage (coalesced) ---
    if (t < 512) {
        const float4 f4 = ((const float4*)(fe + o0 * Cc))[t];
        uint2 p;
        p.x = pk_rn(f4.x, f4.y);
        p.y = pk_rn(f4.z, f4.w);
        ((uint2*)fe_h)[t] = p;
    }
    ((uint4*)A_h)[t] = ((const uint4*)A16)[t];   // 4096 uints = 1024 uint4
    if (t < Hh)  w2_s[t] = 0.5f * W2[t];
    if (t < TOo) fb_s[t] = fb[o0 + t];
    const float b2v = b2[0];
    __syncthreads();

    // --- G phase: h = t&127, og = t>>7 (0..7), 8 o per thread, fdot2 inner ---
    {
        const int h  = t & 127;
        const int og = t >> 7;
        h2 w1f2[Cc / 2];
#pragma unroll
        for (int cc = 0; cc < Cc / 2; ++cc) {
            const float x = W1[(Hh + 2 * cc) * Hh + h];       // coalesced, L2-hot
            const float y = W1[(Hh + 2 * cc + 1) * Hh + h];
            w1f2[cc] = as_h2(pk_rn(x, y));
        }
        const float w1b = W1[(Hh + Cc) * Hh + h];
        const float b1h = b1[h];
#pragma unroll
        for (int j = 0; j < 8; ++j) {
            const int o = og * 8 + j;
            float g = fmaf(fb_s[o], w1b, b1h);
            const uint4* q4 = (const uint4*)&fe_h[o][0];      // broadcast reads
#pragma unroll
            for (int cc = 0; cc < 4; ++cc) {
                const uint4 q = q4[cc];
                g = __builtin_amdgcn_fdot2(as_h2(q.x), w1f2[4 * cc + 0], g, false);
                g = __builtin_amdgcn_fdot2(as_h2(q.y), w1f2[4 * cc + 1], g, false);
                g = __builtin_amdgcn_fdot2(as_h2(q.z), w1f2[4 * cc + 2], g, false);
                g = __builtin_amdgcn_fdot2(as_h2(q.w), w1f2[4 * cc + 3], g, false);
            }
            gT[h][o] = g;   // bank = (h+o)%32 rotated: conflict-free
        }
    }
    __syncthreads();

    // --- main loop: 16 waves = 4 h-slices x 4 b-groups, lane = o ---
    const int lane = t & 63;
    const int wave = __builtin_amdgcn_readfirstlane(t >> 6);
    const int hh   = wave & 3;        // h-slice 0..3
    const int bg   = wave >> 2;       // b-group 0..3
    const int h0   = hh * 32;
    const int b0   = bg * 16;

    float gvf[32];
#pragma unroll
    for (int k = 0; k < 32; ++k)
        gvf[k] = gT[h0 + k][lane];    // stride-65 rotation: conflict-free

    float w2f[32];
#pragma unroll
    for (int k = 0; k < 8; ++k) {
        const float4 w4 = ((const float4*)(w2_s + h0))[k];  // broadcast
        w2f[4 * k + 0] = w4.x; w2f[4 * k + 1] = w4.y;
        w2f[4 * k + 2] = w4.z; w2f[4 * k + 3] = w4.w;
    }

    // linear g-term in f32 (exact half of the relu identity)
    float sg = 0.f;
#pragma unroll
    for (int k = 0; k < 32; ++k)
        sg = fmaf(w2f[k], gvf[k], sg);

    // pack g and w2 to half2 for the |A+g| term
    h2 g2[16], w22[16];
#pragma unroll
    for (int k = 0; k < 16; ++k) {
        g2[k]  = as_h2(pk_rn(gvf[2 * k], gvf[2 * k + 1]));
        w22[k] = as_h2(pk_rn(w2f[2 * k], w2f[2 * k + 1]));
    }

    float acc[16];
#pragma unroll
    for (int bi = 0; bi < 16; ++bi) acc[bi] = sg;

#pragma unroll
    for (int jc = 0; jc < 4; ++jc) {            // 8 h (4 half2) per jc
#pragma unroll
        for (int bi = 0; bi < 16; ++bi) {
            // wave-uniform address -> ds_read_b128 broadcast, conflict-free
            const uint4 a4 = *(const uint4*)&A_h[b0 + bi][hh * 16 + 4 * jc];
            acc[bi] = __builtin_amdgcn_fdot2(habs2(as_h2(a4.x) + g2[4 * jc + 0]),
                                             w22[4 * jc + 0], acc[bi], false);
            acc[bi] = __builtin_amdgcn_fdot2(habs2(as_h2(a4.y) + g2[4 * jc + 1]),
                                             w22[4 * jc + 1], acc[bi], false);
            acc[bi] = __builtin_amdgcn_fdot2(habs2(as_h2(a4.z) + g2[4 * jc + 2]),
                                             w22[4 * jc + 2], acc[bi], false);
            acc[bi] = __builtin_amdgcn_fdot2(habs2(as_h2(a4.w) + g2[4 * jc + 3]),
                                             w22[4 * jc + 3], acc[bi], false);
        }
    }

#pragma unroll
    for (int bi = 0; bi < 16; ++bi)
        part[hh][b0 + bi][lane] = acc[bi];   // lanes consecutive: free
    __syncthreads();

    // --- uniform combine: each wave handles 4 b ---
#pragma unroll
    for (int q = 0; q < 4; ++q) {
        const int b = wave * 4 + q;
        const float r = part[0][b][lane] + part[1][b][lane]
                      + part[2][b][lane] + part[3][b][lane];
        out[b * Oo + o0 + lane] = r + SA2w[b] + b2v;   // coalesced 256B
    }
}

extern "C" void kernel_launch(void* const* d_in, const int* in_sizes, int n_in,
                              void* d_out, int out_size, void* d_ws, size_t ws_size,
                              hipStream_t stream) {
    (void)in_sizes; (void)n_in; (void)out_size; (void)ws_size;
    const float* z   = (const float*)d_in[0];   // (64,32)
    const float* fe  = (const float*)d_in[1];   // (16384,32)
    const float* fb  = (const float*)d_in[2];   // (16384,1)
    const float* Wz  = (const float*)d_in[3];   // (32,128)
    const float* bz  = (const float*)d_in[4];   // (128,)
    const float* W1  = (const float*)d_in[5];   // (161,128)
    const float* b1  = (const float*)d_in[6];   // (128,)
    const float* W2  = (const float*)d_in[7];   // (128,1)
    const float* b2  = (const float*)d_in[8];   // (1,)
    float* out       = (float*)d_out;           // (64,16384)
    unsigned* A16    = (unsigned*)d_ws;         // 64*64 uints (half2 pairs)
    float* SA2w      = (float*)(A16 + Bb * (Hh / 2));  // 64 floats

    prep_kernel<<<Bb / 2, 256, 0, stream>>>(z, Wz, bz, W1, W2, A16, SA2w);
    main_kernel<<<Oo / TOo, NT, 0, stream>>>(A16, SA2w, fe, fb, W1, b1, W2, b2, out);
}